// Round 9
// baseline (352.991 us; speedup 1.0000x reference)
//
#include <hip/hip_runtime.h>
#include <cstdint>

#define RFL(x) __builtin_amdgcn_readfirstlane(x)

// ---------------- problem constants ----------------
static constexpr int B  = 512;
static constexpr int C0 = 4,  H0 = 84, W0 = 84;
static constexpr int C1 = 32, H1 = 20, W1 = 20, P1 = H1 * W1;  // 400
static constexpr int C2 = 64, H2 = 9,  W2 = 9,  P2 = H2 * W2;  // 81
static constexpr int C3 = 64, H3 = 7,  W3 = 7,  P3 = H3 * W3;  // 49
static constexpr int K  = C3 * P3;   // 3136
static constexpr int O  = 512;

// ---------------- workspace layout (bytes) ----------------
// s1c: class bit-planes [b][pix][c(8)][half(2)] u16  (32B per (b,pix))
// s2p: t bit-planes     [b][pix][t(8)] u64           (64B per (b,pix))
static constexpr size_t OFF_S1   = 0;                        // 6,553,600
static constexpr size_t OFF_S2   = 6553600;                  // B*P2*64 = 2,654,208
static constexpr size_t OFF_S3   = OFF_S2 + 2654208;         // B*P3*C3 u8 = 1,605,632
static constexpr size_t OFF_W2T  = OFF_S3 + 1605632;         // 512*64 f32
static constexpr size_t OFF_W3T  = OFF_W2T + 131072;         // 576*64 f32
static constexpr size_t OFF_FW1T = OFF_W3T + 147456;         // 3136*512 f32 = 6,422,528
static constexpr size_t OFF_W1T  = OFF_FW1T + 6422528;       // 8192 f32

// ---------------- weight transposes ----------------
// w1T layout: [half][ic][ky][o(16)][kx(8)] -> 128 contiguous floats per (half,ic,ky)
__global__ void k_prep_w1(const float* __restrict__ w1, float* __restrict__ w1T) {
    int n = blockIdx.x * 256 + threadIdx.x;              // 8192 = 2*4*8*16*8
    if (n >= 8192) return;
    int kx = n & 7, o = (n >> 3) & 15, ky = (n >> 7) & 7, ic = (n >> 10) & 3, half = n >> 12;
    int oc = half * 16 + o;
    w1T[n] = w1[((oc * 4 + ic) * 8 + ky) * 8 + kx];
}

__global__ void k_prep_w2(const float* __restrict__ w2, float* __restrict__ w2T) {
    int idx = blockIdx.x * 256 + threadIdx.x;            // 64*32*16 = 32768
    if (idx >= 64 * 32 * 16) return;
    int oc = idx >> 9, r = idx & 511;
    int ic = r >> 4, ky = (r >> 2) & 3, kx = r & 3;
    w2T[((ky * 4 + kx) * 32 + ic) * 64 + oc] = w2[idx];
}

__global__ void k_prep_w3(const float* __restrict__ w3, float* __restrict__ w3T) {
    int idx = blockIdx.x * 256 + threadIdx.x;            // 64*64*9 = 36864
    if (idx >= 64 * 64 * 9) return;
    int oc = idx / 576, r = idx - oc * 576;
    int ic = r / 9, rr = r - ic * 9;
    int ky = rr / 3, kx = rr - ky * 3;
    w3T[((ky * 3 + kx) * 64 + ic) * 64 + oc] = w3[idx];
}

// pure [O][K] -> [K][O] transpose, LDS-tiled 64x64, coalesced both sides
__global__ __launch_bounds__(256) void k_prep_fw1(const float* __restrict__ fw1,
                                                  float* __restrict__ fw1T) {
    __shared__ float tile[64][65];
    int ot = blockIdx.x & 7;            // 8 o-tiles
    int it = blockIdx.x >> 3;           // 49 i-tiles
    int tr = threadIdx.x >> 6;          // 0..3
    int tc = threadIdx.x & 63;
    #pragma unroll
    for (int r = 0; r < 16; r++) {
        int ol = r * 4 + tr;
        tile[ol][tc] = fw1[(size_t)(ot * 64 + ol) * K + it * 64 + tc];
    }
    __syncthreads();
    #pragma unroll
    for (int r = 0; r < 16; r++) {
        int il = r * 4 + tr;
        fw1T[(size_t)(it * 64 + il) * O + ot * 64 + tc] = tile[tc][il];
    }
}

// ---------------- conv1 (dense) + LIF1 -> class bit-planes ----------------
// Block = (image, oy-half, oc-half).  WEIGHTS IN LDS (16 KB half-slice staged
// once; uniform-address ds_read_b128 = wave broadcast, conflict-free, in-order
// lgkm -> counted waits pipeline).  x band staged to LDS per ic as before.
__global__ __launch_bounds__(256) void k_conv1(const float* __restrict__ x,
                                               const float* __restrict__ w1T,
                                               const float* __restrict__ b1,
                                               uint8_t* __restrict__ s1c) {
    __shared__ __align__(16) float wsl[4096];            // 16 KB weights (this half)
    __shared__ __align__(16) float xs[44 * 84];          // 14784 B x band
    int bid  = blockIdx.x;             // 0..2047
    int half = bid & 1;                // oc half   (scalar)
    int oyh  = (bid >> 1) & 1;         // oy half   (scalar)
    int b    = bid >> 2;               // image     (scalar)
    int tid  = threadIdx.x;
    int p    = tid;                    // local pixel 0..199 valid
    int oyl  = p / W1, ox = p - oyl * W1;
    const float* xb = x + (size_t)b * 28224 + oyh * 3360;   // 40 rows * 84
    const float* wh = w1T + half * 4096;                     // scalar base

    // stage this half's weights once (1024 float4, 4 per thread, coalesced)
    {
        const float4* src = (const float4*)wh;
        #pragma unroll
        for (int j = 0; j < 4; j++) ((float4*)wsl)[tid + j * 256] = src[tid + j * 256];
    }

    float acc[16];
    #pragma unroll
    for (int o = 0; o < 16; o++) acc[o] = b1[half * 16 + o];

    #pragma unroll
    for (int ic = 0; ic < C0; ic++) {
        __syncthreads();               // weights staged / previous compute done
        const float4* src = (const float4*)(xb + ic * 7056);
        #pragma unroll
        for (int j = tid; j < 924; j += 256) ((float4*)xs)[j] = src[j];
        __syncthreads();
        if (p < 200) {
            #pragma unroll
            for (int ky = 0; ky < 8; ky++) {
                const float* lrow = xs + (oyl * 4 + ky) * 84 + ox * 4;
                float4 a0 = *(const float4*)lrow;
                float4 a1 = *(const float4*)(lrow + 4);
                float xv[8] = {a0.x, a0.y, a0.z, a0.w, a1.x, a1.y, a1.z, a1.w};
                const float* wl = wsl + ic * 1024 + ky * 128;   // uniform LDS base
                #pragma unroll
                for (int o = 0; o < 16; o++) {
                    float4 w0 = *(const float4*)(wl + o * 8);       // broadcast b128
                    float4 w1 = *(const float4*)(wl + o * 8 + 4);
                    float s = acc[o];
                    s = fmaf(w0.x, xv[0], s); s = fmaf(w0.y, xv[1], s);
                    s = fmaf(w0.z, xv[2], s); s = fmaf(w0.w, xv[3], s);
                    s = fmaf(w1.x, xv[4], s); s = fmaf(w1.y, xv[5], s);
                    s = fmaf(w1.z, xv[6], s); s = fmaf(w1.w, xv[7], s);
                    acc[o] = s;
                }
            }
        }
    }
    if (p >= 200) return;

    // LIF (constant drive, hard reset) -> first-spike class planes
    uint32_t pl[8] = {0, 0, 0, 0, 0, 0, 0, 0};
    #pragma unroll
    for (int o = 0; o < 16; o++) {
        float h = acc[o], v = 0.f;
        uint32_t mm = 0;
        #pragma unroll
        for (int t = 0; t < 8; t++) {
            v = v + (h - v) * 0.5f;              // exact ref op order
            bool sp = (v >= 1.0f);
            mm |= sp ? (1u << t) : 0u;
            v = sp ? 0.f : v;
        }
        uint32_t fs = mm & (0u - mm);            // lowest set bit (class indicator)
        #pragma unroll
        for (int c = 0; c < 8; c++) pl[c] |= ((fs >> c) & 1u) << o;
    }
    int pg = oyh * 200 + p;                      // global pixel
    ushort* outp = (ushort*)(s1c + (size_t)(b * P1 + pg) * 32);
    #pragma unroll
    for (int c = 0; c < 8; c++) outp[c * 2 + half] = (ushort)pl[c];
}

// ---------------- conv2 + LIF2 (class-sparse, lane = oc) -> t bit-planes ------
// 1 weight-load + 1 add per active input; y_t from class sums; output via ballot.
__global__ __launch_bounds__(256) void k_conv2(const uint8_t* __restrict__ s1c,
                                               const float* __restrict__ w2T,
                                               const float* __restrict__ b2,
                                               uint8_t* __restrict__ s2p) {
    int wid = blockIdx.x * 4 + (threadIdx.x >> 6);   // 0..41471  (b,pix)
    int lane = threadIdx.x & 63;                     // = oc
    int b = wid / P2, pix = wid - b * P2;
    int oy = pix / W2, ox = pix - oy * W2;
    float A[8];
    #pragma unroll
    for (int c = 0; c < 8; c++) A[c] = 0.f;
    #pragma unroll
    for (int ky = 0; ky < 4; ky++) {
        #pragma unroll
        for (int kx = 0; kx < 4; kx++) {
            int mofs = RFL((b * P1 + (oy * 2 + ky) * W1 + (ox * 2 + kx)) * 32);
            const uint32_t* mp = (const uint32_t*)(s1c + mofs);   // 8 class words (scalar)
            const float* wp = w2T + (ky * 4 + kx) * 32 * 64 + lane;
            #pragma unroll
            for (int c = 0; c < 8; c++) {
                uint32_t w = mp[c];
                while (w) {                        // wave-uniform loop
                    int ic = __builtin_ctz(w);
                    w &= w - 1;
                    A[c] += wp[ic * 64];           // coalesced 256B, 1 add/event
                }
            }
        }
    }
    // y_t from periodic class patterns (t1 = c+1, spikes at steps t1, 2*t1, ...)
    float y[8];
    y[0] = A[0];
    y[1] = A[0] + A[1];
    y[2] = A[0] + A[2];
    y[3] = A[0] + A[1] + A[3];
    y[4] = A[0] + A[4];
    y[5] = A[0] + A[1] + A[2] + A[5];
    y[6] = A[0] + A[6];
    y[7] = A[0] + A[1] + A[3] + A[7];

    float bo = b2[lane];
    uint32_t mout = 0;
    float v = 0.f;
    #pragma unroll
    for (int t = 0; t < 8; t++) {
        float yt = y[t] + bo;
        v = v + (yt - v) * 0.5f;
        bool sp = (v >= 1.0f);
        mout |= sp ? (1u << t) : 0u;
        v = sp ? 0.f : v;
    }
    // emit t bit-planes: bit ic of plane t = spike(ic=lane, t)
    unsigned long long* op = (unsigned long long*)(s2p + (size_t)(b * P2 + pix) * 64);
    #pragma unroll
    for (int t = 0; t < 8; t++) {
        unsigned long long bm = __ballot((mout >> t) & 1u);
        if (lane == 0) op[t] = bm;
    }
}

// ---------------- conv3 + LIF3 (event-sparse via t bit-planes, lane = oc) -----
// Per event (spike): 1 scalar ctz + 1 coalesced weight load + 1 v_add.
__global__ __launch_bounds__(256) void k_conv3(const uint8_t* __restrict__ s2p,
                                               const float* __restrict__ w3T,
                                               const float* __restrict__ b3,
                                               uint8_t* __restrict__ s3m) {
    int wid = blockIdx.x * 4 + (threadIdx.x >> 6);   // 0..25087 (b,pix)
    int lane = threadIdx.x & 63;
    int b = wid / P3, pix = wid - b * P3;
    int oy = pix / W3, ox = pix - oy * W3;
    float A[8];
    #pragma unroll
    for (int t = 0; t < 8; t++) A[t] = 0.f;
    #pragma unroll
    for (int ky = 0; ky < 3; ky++) {
        #pragma unroll
        for (int kx = 0; kx < 3; kx++) {
            int mofs = RFL((b * P2 + (oy + ky) * W2 + (ox + kx)) * 64);
            const unsigned long long* mp = (const unsigned long long*)(s2p + mofs);
            const float* wp = w3T + (ky * 3 + kx) * 64 * 64 + lane;
            #pragma unroll
            for (int t = 0; t < 8; t++) {
                unsigned long long m = mp[t];       // scalar u64 plane
                while (m) {                         // wave-uniform event scan
                    int ic = __builtin_ctzll(m);
                    m &= m - 1;
                    A[t] += wp[ic * 64];            // coalesced, 1 add/event
                }
            }
        }
    }
    float bo = b3[lane];
    uint32_t mout = 0;
    float v = 0.f;
    #pragma unroll
    for (int t = 0; t < 8; t++) {
        float y = A[t] + bo;
        v = v + (y - v) * 0.5f;
        bool sp = (v >= 1.0f);
        mout |= sp ? (1u << t) : 0u;
        v = sp ? 0.f : v;
    }
    s3m[(size_t)(b * P3 + pix) * 64 + lane] = (uint8_t)mout;
}

// ---------------- fc1 + LIF4 + mean + fc2 ----------------
// block = 4 waves, one batch; K split 784/wave; LDS partial-sum reduce; wave 0 finishes.
__global__ __launch_bounds__(256) void k_fc(const uint8_t* __restrict__ s3m,
                                            const float* __restrict__ fw1T,
                                            const float* __restrict__ fb1,
                                            const float* __restrict__ fw2,
                                            const float* __restrict__ fb2,
                                            float* __restrict__ out) {
    __shared__ float red[3][64][65];
    int b = blockIdx.x;
    int w = threadIdx.x >> 6;                         // 0..3
    int lane = threadIdx.x & 63;
    float acc[8][8];                                  // [j][t]
    #pragma unroll
    for (int j = 0; j < 8; j++)
        #pragma unroll
        for (int t = 0; t < 8; t++) acc[j][t] = 0.f;

    int ibeg = w * 784;                               // 784 = 49*16
    for (int i0 = ibeg; i0 < ibeg + 784; i0 += 16) {
        int base = RFL(b * K + i0);
        const uint32_t* mp = (const uint32_t*)(s3m + base);
        #pragma unroll
        for (int d = 0; d < 4; d++) {
            uint32_t md = mp[d];
            if (md == 0) continue;
            #pragma unroll
            for (int q = 0; q < 4; q++) {
                uint32_t m = (md >> (q * 8)) & 0xffu;
                if (m == 0) continue;
                int i_our = i0 + d * 4 + q;           // = pix*64 + c
                int pix = i_our >> 6, c = i_our & 63;
                const float4* wp = (const float4*)(fw1T + (size_t)(c * 49 + pix) * O + lane * 8);
                float4 wa = wp[0], wb = wp[1];
                float wv[8] = {wa.x, wa.y, wa.z, wa.w, wb.x, wb.y, wb.z, wb.w};
                #pragma unroll
                for (int t = 0; t < 8; t++) {
                    if (m & (1u << t)) {
                        #pragma unroll
                        for (int j = 0; j < 8; j++) acc[j][t] += wv[j];
                    }
                }
            }
        }
    }

    if (w > 0) {
        #pragma unroll
        for (int j = 0; j < 8; j++)
            #pragma unroll
            for (int t = 0; t < 8; t++) red[w - 1][lane][j * 8 + t] = acc[j][t];
    }
    __syncthreads();
    if (w != 0) return;

    #pragma unroll
    for (int ww = 0; ww < 3; ww++)
        #pragma unroll
        for (int j = 0; j < 8; j++)
            #pragma unroll
            for (int t = 0; t < 8; t++) acc[j][t] += red[ww][lane][j * 8 + t];

    float msum[8];
    #pragma unroll
    for (int j = 0; j < 8; j++) {
        float yb = fb1[lane * 8 + j];
        float v = 0.f, cnt = 0.f;
        #pragma unroll
        for (int t = 0; t < 8; t++) {
            float y = acc[j][t] + yb;
            v = v + (y - v) * 0.5f;
            bool sp = (v >= 1.0f);
            cnt += sp ? 1.f : 0.f;
            v = sp ? 0.f : v;
        }
        msum[j] = cnt * 0.125f;                       // exact: count/8
    }
    #pragma unroll
    for (int k = 0; k < 6; k++) {
        const float* wr = fw2 + k * O + lane * 8;
        float pv = 0.f;
        #pragma unroll
        for (int j = 0; j < 8; j++) pv += msum[j] * wr[j];
        #pragma unroll
        for (int off = 32; off > 0; off >>= 1) pv += __shfl_down(pv, off, 64);
        if (lane == 0) out[b * 6 + k] = pv + fb2[k];
    }
}

// ---------------- launch ----------------
extern "C" void kernel_launch(void* const* d_in, const int* in_sizes, int n_in,
                              void* d_out, int out_size, void* d_ws, size_t ws_size,
                              hipStream_t stream) {
    const float* x   = (const float*)d_in[0];
    const float* w1  = (const float*)d_in[1];
    const float* b1  = (const float*)d_in[2];
    const float* w2  = (const float*)d_in[3];
    const float* b2  = (const float*)d_in[4];
    const float* w3  = (const float*)d_in[5];
    const float* b3  = (const float*)d_in[6];
    const float* fw1 = (const float*)d_in[7];
    const float* fb1 = (const float*)d_in[8];
    const float* fw2 = (const float*)d_in[9];
    const float* fb2 = (const float*)d_in[10];
    float* out = (float*)d_out;

    uint8_t* ws   = (uint8_t*)d_ws;
    uint8_t* s1c  = ws + OFF_S1;
    uint8_t* s2p  = ws + OFF_S2;
    uint8_t* s3m  = ws + OFF_S3;
    float*   w2T  = (float*)(ws + OFF_W2T);
    float*   w3T  = (float*)(ws + OFF_W3T);
    float*   fw1T = (float*)(ws + OFF_FW1T);
    float*   w1T  = (float*)(ws + OFF_W1T);

    hipLaunchKernelGGL(k_prep_w1,  dim3(32),    dim3(256), 0, stream, w1, w1T);
    hipLaunchKernelGGL(k_prep_w2,  dim3(128),   dim3(256), 0, stream, w2, w2T);
    hipLaunchKernelGGL(k_prep_w3,  dim3(144),   dim3(256), 0, stream, w3, w3T);
    hipLaunchKernelGGL(k_prep_fw1, dim3(392),   dim3(256), 0, stream, fw1, fw1T);
    hipLaunchKernelGGL(k_conv1,    dim3(2048),  dim3(256), 0, stream, x, w1T, b1, s1c);
    hipLaunchKernelGGL(k_conv2,    dim3(10368), dim3(256), 0, stream, s1c, w2T, b2, s2p);
    hipLaunchKernelGGL(k_conv3,    dim3(6272),  dim3(256), 0, stream, s2p, w3T, b3, s3m);
    hipLaunchKernelGGL(k_fc,       dim3(512),   dim3(256), 0, stream, s3m, fw1T, fb1, fw2, fb2, out);
}

// Round 10
// 264.334 us; speedup vs baseline: 1.3354x; 1.3354x over previous
//
#include <hip/hip_runtime.h>
#include <cstdint>

#define RFL(x) __builtin_amdgcn_readfirstlane(x)

// ---------------- problem constants ----------------
static constexpr int B  = 512;
static constexpr int C0 = 4,  H0 = 84, W0 = 84;
static constexpr int C1 = 32, H1 = 20, W1 = 20, P1 = H1 * W1;  // 400
static constexpr int C2 = 64, H2 = 9,  W2 = 9,  P2 = H2 * W2;  // 81
static constexpr int C3 = 64, H3 = 7,  W3 = 7,  P3 = H3 * W3;  // 49
static constexpr int K  = C3 * P3;   // 3136
static constexpr int O  = 512;

// ---------------- workspace layout (bytes) ----------------
// s1c: class bit-planes [b][pix][c(8)] u32, bit = oc  (32B per (b,pix))
// s2p: t bit-planes     [b][pix][t(8)] u64            (64B per (b,pix))
static constexpr size_t OFF_S1   = 0;                        // 6,553,600
static constexpr size_t OFF_S2   = 6553600;                  // B*P2*64 = 2,654,208
static constexpr size_t OFF_S3   = OFF_S2 + 2654208;         // B*P3*C3 u8 = 1,605,632
static constexpr size_t OFF_W2T  = OFF_S3 + 1605632;         // 512*64 f32
static constexpr size_t OFF_W3T  = OFF_W2T + 131072;         // 576*64 f32
static constexpr size_t OFF_FW1T = OFF_W3T + 147456;         // 3136*512 f32 = 6,422,528
static constexpr size_t OFF_W1T  = OFF_FW1T + 6422528;       // 8192 f32

// ---------------- weight transposes ----------------
// w1T layout: [o8(4)][ic(4)][ky(8)][o(8)][kx(8)] -> 64 contiguous floats/(o8,ic,ky)
__global__ void k_prep_w1(const float* __restrict__ w1, float* __restrict__ w1T) {
    int n = blockIdx.x * 256 + threadIdx.x;              // 8192
    if (n >= 8192) return;
    int kx = n & 7, o = (n >> 3) & 7, ky = (n >> 6) & 7, ic = (n >> 9) & 3, o8 = n >> 11;
    int oc = o8 * 8 + o;
    w1T[n] = w1[((oc * 4 + ic) * 8 + ky) * 8 + kx];
}

__global__ void k_prep_w2(const float* __restrict__ w2, float* __restrict__ w2T) {
    int idx = blockIdx.x * 256 + threadIdx.x;            // 64*32*16 = 32768
    if (idx >= 64 * 32 * 16) return;
    int oc = idx >> 9, r = idx & 511;
    int ic = r >> 4, ky = (r >> 2) & 3, kx = r & 3;
    w2T[((ky * 4 + kx) * 32 + ic) * 64 + oc] = w2[idx];
}

__global__ void k_prep_w3(const float* __restrict__ w3, float* __restrict__ w3T) {
    int idx = blockIdx.x * 256 + threadIdx.x;            // 64*64*9 = 36864
    if (idx >= 64 * 64 * 9) return;
    int oc = idx / 576, r = idx - oc * 576;
    int ic = r / 9, rr = r - ic * 9;
    int ky = rr / 3, kx = rr - ky * 3;
    w3T[((ky * 3 + kx) * 64 + ic) * 64 + oc] = w3[idx];
}

// pure [O][K] -> [K][O] transpose, LDS-tiled 64x64, coalesced both sides
__global__ __launch_bounds__(256) void k_prep_fw1(const float* __restrict__ fw1,
                                                  float* __restrict__ fw1T) {
    __shared__ float tile[64][65];
    int ot = blockIdx.x & 7;            // 8 o-tiles
    int it = blockIdx.x >> 3;           // 49 i-tiles
    int tr = threadIdx.x >> 6;          // 0..3
    int tc = threadIdx.x & 63;
    #pragma unroll
    for (int r = 0; r < 16; r++) {
        int ol = r * 4 + tr;
        tile[ol][tc] = fw1[(size_t)(ot * 64 + ol) * K + it * 64 + tc];
    }
    __syncthreads();
    #pragma unroll
    for (int r = 0; r < 16; r++) {
        int il = r * 4 + tr;
        fw1T[(size_t)(it * 64 + il) * O + ot * 64 + tc] = tile[tc][il];
    }
}

// ---------------- conv1 (dense) + LIF1 -> class bit-planes ----------------
// Register-blocked: thread = 4 adjacent pixels (quad) x 8 oc.  Per (ic,ky):
// 5 global float4 (20 contiguous x floats, L1) + 64 weight floats (4x
// s_load_dwordx16, wave-uniform via o8 = blk/200) feeding 256 independent
// FMAs.  No LDS, no barriers -> compiler software-pipelines freely.
// Jobs: 512 img * 100 quads * 4 o8 = 204800 threads = 800 blocks, 0 dead lanes.
__global__ __launch_bounds__(256) void k_conv1(const float* __restrict__ x,
                                               const float* __restrict__ w1T,
                                               const float* __restrict__ b1,
                                               uint8_t* __restrict__ s1c) {
    int blk = blockIdx.x;                    // 0..799
    int o8  = blk / 200;                     // scalar 0..3
    int rest = (blk - o8 * 200) * 256 + threadIdx.x;   // 0..51199
    int img = rest / 100, quad = rest - img * 100;
    int oy = quad / 5, qx = quad - oy * 5;   // qx: 4-pixel group in x
    const float* xb = x + (size_t)img * 28224;
    const float* wh = w1T + o8 * 2048;       // scalar base -> s_load

    float acc[4][8];                         // [pix][o]
    #pragma unroll
    for (int pp = 0; pp < 4; pp++)
        #pragma unroll
        for (int o = 0; o < 8; o++) acc[pp][o] = b1[o8 * 8 + o];

    #pragma unroll
    for (int ic = 0; ic < C0; ic++) {
        #pragma unroll
        for (int ky = 0; ky < 8; ky++) {
            const float* rp = xb + (ic * H0 + oy * 4 + ky) * W0 + qx * 16;
            float xv[20];
            #pragma unroll
            for (int j = 0; j < 5; j++) {
                float4 a = *(const float4*)(rp + j * 4);
                xv[j * 4 + 0] = a.x; xv[j * 4 + 1] = a.y;
                xv[j * 4 + 2] = a.z; xv[j * 4 + 3] = a.w;
            }
            const float* wb = wh + (ic * 8 + ky) * 64;   // 64 contiguous, uniform
            #pragma unroll
            for (int o = 0; o < 8; o++) {
                #pragma unroll
                for (int pp = 0; pp < 4; pp++) {
                    float s = acc[pp][o];
                    #pragma unroll
                    for (int kx = 0; kx < 8; kx++)
                        s = fmaf(wb[o * 8 + kx], xv[pp * 4 + kx], s);
                    acc[pp][o] = s;
                }
            }
        }
    }

    // LIF (constant drive, hard reset) -> first-spike class planes.
    // This thread owns byte o8 of each of the 8 class words, for 4 pixels.
    #pragma unroll
    for (int pp = 0; pp < 4; pp++) {
        uint32_t byc[8] = {0, 0, 0, 0, 0, 0, 0, 0};
        #pragma unroll
        for (int o = 0; o < 8; o++) {
            float h = acc[pp][o], v = 0.f;
            uint32_t mm = 0;
            #pragma unroll
            for (int t = 0; t < 8; t++) {
                v = v + (h - v) * 0.5f;          // exact ref op order
                bool sp = (v >= 1.0f);
                mm |= sp ? (1u << t) : 0u;
                v = sp ? 0.f : v;
            }
            uint32_t fs = mm & (0u - mm);        // lowest set bit (class indicator)
            #pragma unroll
            for (int c = 0; c < 8; c++) byc[c] |= ((fs >> c) & 1u) << o;
        }
        int pix = oy * W1 + qx * 4 + pp;
        uint8_t* op = s1c + (size_t)(img * P1 + pix) * 32 + o8;
        #pragma unroll
        for (int c = 0; c < 8; c++) op[c * 4] = (uint8_t)byc[c];
    }
}

// ---------------- conv2 + LIF2 (class-sparse, lane = oc) -> t bit-planes ------
// 1 weight-load + 1 add per active input; y_t from class sums; output via ballot.
__global__ __launch_bounds__(256) void k_conv2(const uint8_t* __restrict__ s1c,
                                               const float* __restrict__ w2T,
                                               const float* __restrict__ b2,
                                               uint8_t* __restrict__ s2p) {
    int wid = blockIdx.x * 4 + (threadIdx.x >> 6);   // 0..41471  (b,pix)
    int lane = threadIdx.x & 63;                     // = oc
    int b = wid / P2, pix = wid - b * P2;
    int oy = pix / W2, ox = pix - oy * W2;
    float A[8];
    #pragma unroll
    for (int c = 0; c < 8; c++) A[c] = 0.f;
    #pragma unroll
    for (int ky = 0; ky < 4; ky++) {
        #pragma unroll
        for (int kx = 0; kx < 4; kx++) {
            int mofs = RFL((b * P1 + (oy * 2 + ky) * W1 + (ox * 2 + kx)) * 32);
            const uint32_t* mp = (const uint32_t*)(s1c + mofs);   // 8 class words (scalar)
            const float* wp = w2T + (ky * 4 + kx) * 32 * 64 + lane;
            #pragma unroll
            for (int c = 0; c < 8; c++) {
                uint32_t w = mp[c];
                while (w) {                        // wave-uniform loop
                    int ic = __builtin_ctz(w);
                    w &= w - 1;
                    A[c] += wp[ic * 64];           // coalesced 256B, 1 add/event
                }
            }
        }
    }
    // y_t from periodic class patterns (t1 = c+1, spikes at steps t1, 2*t1, ...)
    float y[8];
    y[0] = A[0];
    y[1] = A[0] + A[1];
    y[2] = A[0] + A[2];
    y[3] = A[0] + A[1] + A[3];
    y[4] = A[0] + A[4];
    y[5] = A[0] + A[1] + A[2] + A[5];
    y[6] = A[0] + A[6];
    y[7] = A[0] + A[1] + A[3] + A[7];

    float bo = b2[lane];
    uint32_t mout = 0;
    float v = 0.f;
    #pragma unroll
    for (int t = 0; t < 8; t++) {
        float yt = y[t] + bo;
        v = v + (yt - v) * 0.5f;
        bool sp = (v >= 1.0f);
        mout |= sp ? (1u << t) : 0u;
        v = sp ? 0.f : v;
    }
    // emit t bit-planes: bit ic of plane t = spike(ic=lane, t)
    unsigned long long* op = (unsigned long long*)(s2p + (size_t)(b * P2 + pix) * 64);
    #pragma unroll
    for (int t = 0; t < 8; t++) {
        unsigned long long bm = __ballot((mout >> t) & 1u);
        if (lane == 0) op[t] = bm;
    }
}

// ---------------- conv3 + LIF3 (event-sparse via t bit-planes, lane = oc) -----
// Per event (spike): 1 scalar ctz + 1 coalesced weight load + 1 v_add.
__global__ __launch_bounds__(256) void k_conv3(const uint8_t* __restrict__ s2p,
                                               const float* __restrict__ w3T,
                                               const float* __restrict__ b3,
                                               uint8_t* __restrict__ s3m) {
    int wid = blockIdx.x * 4 + (threadIdx.x >> 6);   // 0..25087 (b,pix)
    int lane = threadIdx.x & 63;
    int b = wid / P3, pix = wid - b * P3;
    int oy = pix / W3, ox = pix - oy * W3;
    float A[8];
    #pragma unroll
    for (int t = 0; t < 8; t++) A[t] = 0.f;
    #pragma unroll
    for (int ky = 0; ky < 3; ky++) {
        #pragma unroll
        for (int kx = 0; kx < 3; kx++) {
            int mofs = RFL((b * P2 + (oy + ky) * W2 + (ox + kx)) * 64);
            const unsigned long long* mp = (const unsigned long long*)(s2p + mofs);
            const float* wp = w3T + (ky * 3 + kx) * 64 * 64 + lane;
            #pragma unroll
            for (int t = 0; t < 8; t++) {
                unsigned long long m = mp[t];       // scalar u64 plane
                while (m) {                         // wave-uniform event scan
                    int ic = __builtin_ctzll(m);
                    m &= m - 1;
                    A[t] += wp[ic * 64];            // coalesced, 1 add/event
                }
            }
        }
    }
    float bo = b3[lane];
    uint32_t mout = 0;
    float v = 0.f;
    #pragma unroll
    for (int t = 0; t < 8; t++) {
        float y = A[t] + bo;
        v = v + (y - v) * 0.5f;
        bool sp = (v >= 1.0f);
        mout |= sp ? (1u << t) : 0u;
        v = sp ? 0.f : v;
    }
    s3m[(size_t)(b * P3 + pix) * 64 + lane] = (uint8_t)mout;
}

// ---------------- fc1 + LIF4 + mean + fc2 ----------------
// block = 4 waves, one batch; K split 784/wave; LDS partial-sum reduce; wave 0 finishes.
__global__ __launch_bounds__(256) void k_fc(const uint8_t* __restrict__ s3m,
                                            const float* __restrict__ fw1T,
                                            const float* __restrict__ fb1,
                                            const float* __restrict__ fw2,
                                            const float* __restrict__ fb2,
                                            float* __restrict__ out) {
    __shared__ float red[3][64][65];
    int b = blockIdx.x;
    int w = threadIdx.x >> 6;                         // 0..3
    int lane = threadIdx.x & 63;
    float acc[8][8];                                  // [j][t]
    #pragma unroll
    for (int j = 0; j < 8; j++)
        #pragma unroll
        for (int t = 0; t < 8; t++) acc[j][t] = 0.f;

    int ibeg = w * 784;                               // 784 = 49*16
    for (int i0 = ibeg; i0 < ibeg + 784; i0 += 16) {
        int base = RFL(b * K + i0);
        const uint32_t* mp = (const uint32_t*)(s3m + base);
        #pragma unroll
        for (int d = 0; d < 4; d++) {
            uint32_t md = mp[d];
            if (md == 0) continue;
            #pragma unroll
            for (int q = 0; q < 4; q++) {
                uint32_t m = (md >> (q * 8)) & 0xffu;
                if (m == 0) continue;
                int i_our = i0 + d * 4 + q;           // = pix*64 + c
                int pix = i_our >> 6, c = i_our & 63;
                const float4* wp = (const float4*)(fw1T + (size_t)(c * 49 + pix) * O + lane * 8);
                float4 wa = wp[0], wb = wp[1];
                float wv[8] = {wa.x, wa.y, wa.z, wa.w, wb.x, wb.y, wb.z, wb.w};
                #pragma unroll
                for (int t = 0; t < 8; t++) {
                    if (m & (1u << t)) {
                        #pragma unroll
                        for (int j = 0; j < 8; j++) acc[j][t] += wv[j];
                    }
                }
            }
        }
    }

    if (w > 0) {
        #pragma unroll
        for (int j = 0; j < 8; j++)
            #pragma unroll
            for (int t = 0; t < 8; t++) red[w - 1][lane][j * 8 + t] = acc[j][t];
    }
    __syncthreads();
    if (w != 0) return;

    #pragma unroll
    for (int ww = 0; ww < 3; ww++)
        #pragma unroll
        for (int j = 0; j < 8; j++)
            #pragma unroll
            for (int t = 0; t < 8; t++) acc[j][t] += red[ww][lane][j * 8 + t];

    float msum[8];
    #pragma unroll
    for (int j = 0; j < 8; j++) {
        float yb = fb1[lane * 8 + j];
        float v = 0.f, cnt = 0.f;
        #pragma unroll
        for (int t = 0; t < 8; t++) {
            float y = acc[j][t] + yb;
            v = v + (y - v) * 0.5f;
            bool sp = (v >= 1.0f);
            cnt += sp ? 1.f : 0.f;
            v = sp ? 0.f : v;
        }
        msum[j] = cnt * 0.125f;                       // exact: count/8
    }
    #pragma unroll
    for (int k = 0; k < 6; k++) {
        const float* wr = fw2 + k * O + lane * 8;
        float pv = 0.f;
        #pragma unroll
        for (int j = 0; j < 8; j++) pv += msum[j] * wr[j];
        #pragma unroll
        for (int off = 32; off > 0; off >>= 1) pv += __shfl_down(pv, off, 64);
        if (lane == 0) out[b * 6 + k] = pv + fb2[k];
    }
}

// ---------------- launch ----------------
extern "C" void kernel_launch(void* const* d_in, const int* in_sizes, int n_in,
                              void* d_out, int out_size, void* d_ws, size_t ws_size,
                              hipStream_t stream) {
    const float* x   = (const float*)d_in[0];
    const float* w1  = (const float*)d_in[1];
    const float* b1  = (const float*)d_in[2];
    const float* w2  = (const float*)d_in[3];
    const float* b2  = (const float*)d_in[4];
    const float* w3  = (const float*)d_in[5];
    const float* b3  = (const float*)d_in[6];
    const float* fw1 = (const float*)d_in[7];
    const float* fb1 = (const float*)d_in[8];
    const float* fw2 = (const float*)d_in[9];
    const float* fb2 = (const float*)d_in[10];
    float* out = (float*)d_out;

    uint8_t* ws   = (uint8_t*)d_ws;
    uint8_t* s1c  = ws + OFF_S1;
    uint8_t* s2p  = ws + OFF_S2;
    uint8_t* s3m  = ws + OFF_S3;
    float*   w2T  = (float*)(ws + OFF_W2T);
    float*   w3T  = (float*)(ws + OFF_W3T);
    float*   fw1T = (float*)(ws + OFF_FW1T);
    float*   w1T  = (float*)(ws + OFF_W1T);

    hipLaunchKernelGGL(k_prep_w1,  dim3(32),    dim3(256), 0, stream, w1, w1T);
    hipLaunchKernelGGL(k_prep_w2,  dim3(128),   dim3(256), 0, stream, w2, w2T);
    hipLaunchKernelGGL(k_prep_w3,  dim3(144),   dim3(256), 0, stream, w3, w3T);
    hipLaunchKernelGGL(k_prep_fw1, dim3(392),   dim3(256), 0, stream, fw1, fw1T);
    hipLaunchKernelGGL(k_conv1,    dim3(800),   dim3(256), 0, stream, x, w1T, b1, s1c);
    hipLaunchKernelGGL(k_conv2,    dim3(10368), dim3(256), 0, stream, s1c, w2T, b2, s2p);
    hipLaunchKernelGGL(k_conv3,    dim3(6272),  dim3(256), 0, stream, s2p, w3T, b3, s3m);
    hipLaunchKernelGGL(k_fc,       dim3(512),   dim3(256), 0, stream, s3m, fw1T, fb1, fw2, fb2, out);
}

// Round 11
// 209.519 us; speedup vs baseline: 1.6848x; 1.2616x over previous
//
#include <hip/hip_runtime.h>
#include <cstdint>

#define RFL(x) __builtin_amdgcn_readfirstlane(x)

// ---------------- problem constants ----------------
static constexpr int B  = 512;
static constexpr int C0 = 4,  H0 = 84, W0 = 84;
static constexpr int C1 = 32, H1 = 20, W1 = 20, P1 = H1 * W1;  // 400
static constexpr int C2 = 64, H2 = 9,  W2 = 9,  P2 = H2 * W2;  // 81
static constexpr int C3 = 64, H3 = 7,  W3 = 7,  P3 = H3 * W3;  // 49
static constexpr int K  = C3 * P3;   // 3136
static constexpr int O  = 512;

// ---------------- workspace layout (bytes) ----------------
// s1c: class bit-planes [b][pix][c(8)] u32, bit = oc  (32B per (b,pix))
// s2p: t bit-planes     [b][pix][t(8)] u64            (64B per (b,pix))
static constexpr size_t OFF_S1   = 0;                        // 6,553,600
static constexpr size_t OFF_S2   = 6553600;                  // B*P2*64 = 2,654,208
static constexpr size_t OFF_S3   = OFF_S2 + 2654208;         // B*P3*C3 u8 = 1,605,632
static constexpr size_t OFF_W2T  = OFF_S3 + 1605632;         // 512*64 f32
static constexpr size_t OFF_W3T  = OFF_W2T + 131072;         // 576*64 f32
static constexpr size_t OFF_FW1T = OFF_W3T + 147456;         // 3136*512 f32 = 6,422,528
static constexpr size_t OFF_W1T  = OFF_FW1T + 6422528;       // 8192 f32

// ---------------- weight transposes ----------------
// w1T layout: [o8(4)][ic(4)][ky(8)][o(8)][kx(8)] -> 64 contiguous floats/(o8,ic,ky)
__global__ void k_prep_w1(const float* __restrict__ w1, float* __restrict__ w1T) {
    int n = blockIdx.x * 256 + threadIdx.x;              // 8192
    if (n >= 8192) return;
    int kx = n & 7, o = (n >> 3) & 7, ky = (n >> 6) & 7, ic = (n >> 9) & 3, o8 = n >> 11;
    int oc = o8 * 8 + o;
    w1T[n] = w1[((oc * 4 + ic) * 8 + ky) * 8 + kx];
}

__global__ void k_prep_w2(const float* __restrict__ w2, float* __restrict__ w2T) {
    int idx = blockIdx.x * 256 + threadIdx.x;            // 64*32*16 = 32768
    if (idx >= 64 * 32 * 16) return;
    int oc = idx >> 9, r = idx & 511;
    int ic = r >> 4, ky = (r >> 2) & 3, kx = r & 3;
    w2T[((ky * 4 + kx) * 32 + ic) * 64 + oc] = w2[idx];
}

__global__ void k_prep_w3(const float* __restrict__ w3, float* __restrict__ w3T) {
    int idx = blockIdx.x * 256 + threadIdx.x;            // 64*64*9 = 36864
    if (idx >= 64 * 64 * 9) return;
    int oc = idx / 576, r = idx - oc * 576;
    int ic = r / 9, rr = r - ic * 9;
    int ky = rr / 3, kx = rr - ky * 3;
    w3T[((ky * 3 + kx) * 64 + ic) * 64 + oc] = w3[idx];
}

// pure [O][K] -> [K][O] transpose, LDS-tiled 64x64, coalesced both sides
__global__ __launch_bounds__(256) void k_prep_fw1(const float* __restrict__ fw1,
                                                  float* __restrict__ fw1T) {
    __shared__ float tile[64][65];
    int ot = blockIdx.x & 7;            // 8 o-tiles
    int it = blockIdx.x >> 3;           // 49 i-tiles
    int tr = threadIdx.x >> 6;          // 0..3
    int tc = threadIdx.x & 63;
    #pragma unroll
    for (int r = 0; r < 16; r++) {
        int ol = r * 4 + tr;
        tile[ol][tc] = fw1[(size_t)(ot * 64 + ol) * K + it * 64 + tc];
    }
    __syncthreads();
    #pragma unroll
    for (int r = 0; r < 16; r++) {
        int il = r * 4 + tr;
        fw1T[(size_t)(it * 64 + il) * O + ot * 64 + tc] = tile[tc][il];
    }
}

// ---------------- conv1 (dense) + LIF1 -> class bit-planes ----------------
// COMPACT-LOOP version (I$-fit): dynamic ic/ky loops (#pragma unroll 1); body =
// 3 x-float4 loads + 64 uniform weight floats (4x s_load_dwordx16) + 128 FMAs
// (~1.5 KB code, looped 32x).  Thread = 2 adjacent pixels x 8 oc.
// Jobs: 4 o8 x 512 img x 200 pairs = 409,600 threads = 1600 blocks, 0 dead lanes.
__global__ __launch_bounds__(256) void k_conv1(const float* __restrict__ x,
                                               const float* __restrict__ w1T,
                                               const float* __restrict__ b1,
                                               uint8_t* __restrict__ s1c) {
    int blk = blockIdx.x;                    // 0..1599
    int o8  = blk / 400;                     // scalar 0..3
    int rest = (blk - o8 * 400) * 256 + threadIdx.x;   // 0..102399
    int img = rest / 200, pair = rest - img * 200;
    int oy  = pair / 10;                     // 2-pixel pairs: 10 per row
    int ox0 = (pair - oy * 10) * 2;
    const float* xb = x + (size_t)img * 28224 + (size_t)(oy * 4) * W0 + ox0 * 4;
    const float* wh = w1T + o8 * 2048;       // scalar base -> s_load

    float acc[2][8];                         // [pix][o]
    #pragma unroll
    for (int pp = 0; pp < 2; pp++)
        #pragma unroll
        for (int o = 0; o < 8; o++) acc[pp][o] = b1[o8 * 8 + o];

    #pragma unroll 1
    for (int ic = 0; ic < C0; ic++) {
        #pragma unroll 1
        for (int ky = 0; ky < 8; ky++) {
            const float* rp = xb + ic * 7056 + ky * W0;
            float4 a0 = *(const float4*)rp;
            float4 a1 = *(const float4*)(rp + 4);
            float4 a2 = *(const float4*)(rp + 8);
            float xv[12] = {a0.x, a0.y, a0.z, a0.w, a1.x, a1.y, a1.z, a1.w,
                            a2.x, a2.y, a2.z, a2.w};
            const float* wb = wh + (ic * 8 + ky) * 64;   // 64 contiguous, uniform
            #pragma unroll
            for (int o = 0; o < 8; o++) {
                #pragma unroll
                for (int pp = 0; pp < 2; pp++) {
                    float s = acc[pp][o];
                    #pragma unroll
                    for (int kx = 0; kx < 8; kx++)
                        s = fmaf(wb[o * 8 + kx], xv[pp * 4 + kx], s);
                    acc[pp][o] = s;
                }
            }
        }
    }

    // LIF (constant drive, hard reset) -> first-spike class planes.
    // This thread owns byte o8 of each of the 8 class words, for 2 pixels.
    #pragma unroll
    for (int pp = 0; pp < 2; pp++) {
        uint32_t byc[8] = {0, 0, 0, 0, 0, 0, 0, 0};
        #pragma unroll
        for (int o = 0; o < 8; o++) {
            float h = acc[pp][o], v = 0.f;
            uint32_t mm = 0;
            #pragma unroll
            for (int t = 0; t < 8; t++) {
                v = v + (h - v) * 0.5f;          // exact ref op order
                bool sp = (v >= 1.0f);
                mm |= sp ? (1u << t) : 0u;
                v = sp ? 0.f : v;
            }
            uint32_t fs = mm & (0u - mm);        // lowest set bit (class indicator)
            #pragma unroll
            for (int c = 0; c < 8; c++) byc[c] |= ((fs >> c) & 1u) << o;
        }
        int pix = oy * W1 + ox0 + pp;
        uint8_t* op = s1c + (size_t)(img * P1 + pix) * 32 + o8;
        #pragma unroll
        for (int c = 0; c < 8; c++) op[c * 4] = (uint8_t)byc[c];
    }
}

// ---------------- conv2 + LIF2 (class-sparse, lane = oc) -> t bit-planes ------
// 1 weight-load + 1 add per active input; y_t from class sums; output via ballot.
__global__ __launch_bounds__(256) void k_conv2(const uint8_t* __restrict__ s1c,
                                               const float* __restrict__ w2T,
                                               const float* __restrict__ b2,
                                               uint8_t* __restrict__ s2p) {
    int wid = blockIdx.x * 4 + (threadIdx.x >> 6);   // 0..41471  (b,pix)
    int lane = threadIdx.x & 63;                     // = oc
    int b = wid / P2, pix = wid - b * P2;
    int oy = pix / W2, ox = pix - oy * W2;
    float A[8];
    #pragma unroll
    for (int c = 0; c < 8; c++) A[c] = 0.f;
    #pragma unroll
    for (int ky = 0; ky < 4; ky++) {
        #pragma unroll
        for (int kx = 0; kx < 4; kx++) {
            int mofs = RFL((b * P1 + (oy * 2 + ky) * W1 + (ox * 2 + kx)) * 32);
            const uint32_t* mp = (const uint32_t*)(s1c + mofs);   // 8 class words (scalar)
            const float* wp = w2T + (ky * 4 + kx) * 32 * 64 + lane;
            #pragma unroll
            for (int c = 0; c < 8; c++) {
                uint32_t w = mp[c];
                while (w) {                        // wave-uniform loop
                    int ic = __builtin_ctz(w);
                    w &= w - 1;
                    A[c] += wp[ic * 64];           // coalesced 256B, 1 add/event
                }
            }
        }
    }
    // y_t from periodic class patterns (t1 = c+1, spikes at steps t1, 2*t1, ...)
    float y[8];
    y[0] = A[0];
    y[1] = A[0] + A[1];
    y[2] = A[0] + A[2];
    y[3] = A[0] + A[1] + A[3];
    y[4] = A[0] + A[4];
    y[5] = A[0] + A[1] + A[2] + A[5];
    y[6] = A[0] + A[6];
    y[7] = A[0] + A[1] + A[3] + A[7];

    float bo = b2[lane];
    uint32_t mout = 0;
    float v = 0.f;
    #pragma unroll
    for (int t = 0; t < 8; t++) {
        float yt = y[t] + bo;
        v = v + (yt - v) * 0.5f;
        bool sp = (v >= 1.0f);
        mout |= sp ? (1u << t) : 0u;
        v = sp ? 0.f : v;
    }
    // emit t bit-planes: bit ic of plane t = spike(ic=lane, t)
    unsigned long long* op = (unsigned long long*)(s2p + (size_t)(b * P2 + pix) * 64);
    #pragma unroll
    for (int t = 0; t < 8; t++) {
        unsigned long long bm = __ballot((mout >> t) & 1u);
        if (lane == 0) op[t] = bm;
    }
}

// ---------------- conv3 + LIF3 (event-sparse via t bit-planes, lane = oc) -----
// Per event (spike): 1 scalar ctz + 1 coalesced weight load + 1 v_add.
__global__ __launch_bounds__(256) void k_conv3(const uint8_t* __restrict__ s2p,
                                               const float* __restrict__ w3T,
                                               const float* __restrict__ b3,
                                               uint8_t* __restrict__ s3m) {
    int wid = blockIdx.x * 4 + (threadIdx.x >> 6);   // 0..25087 (b,pix)
    int lane = threadIdx.x & 63;
    int b = wid / P3, pix = wid - b * P3;
    int oy = pix / W3, ox = pix - oy * W3;
    float A[8];
    #pragma unroll
    for (int t = 0; t < 8; t++) A[t] = 0.f;
    #pragma unroll
    for (int ky = 0; ky < 3; ky++) {
        #pragma unroll
        for (int kx = 0; kx < 3; kx++) {
            int mofs = RFL((b * P2 + (oy + ky) * W2 + (ox + kx)) * 64);
            const unsigned long long* mp = (const unsigned long long*)(s2p + mofs);
            const float* wp = w3T + (ky * 3 + kx) * 64 * 64 + lane;
            #pragma unroll
            for (int t = 0; t < 8; t++) {
                unsigned long long m = mp[t];       // scalar u64 plane
                while (m) {                         // wave-uniform event scan
                    int ic = __builtin_ctzll(m);
                    m &= m - 1;
                    A[t] += wp[ic * 64];            // coalesced, 1 add/event
                }
            }
        }
    }
    float bo = b3[lane];
    uint32_t mout = 0;
    float v = 0.f;
    #pragma unroll
    for (int t = 0; t < 8; t++) {
        float y = A[t] + bo;
        v = v + (y - v) * 0.5f;
        bool sp = (v >= 1.0f);
        mout |= sp ? (1u << t) : 0u;
        v = sp ? 0.f : v;
    }
    s3m[(size_t)(b * P3 + pix) * 64 + lane] = (uint8_t)mout;
}

// ---------------- fc1 + LIF4 + mean + fc2 ----------------
// block = 4 waves, one batch; K split 784/wave; LDS partial-sum reduce; wave 0 finishes.
__global__ __launch_bounds__(256) void k_fc(const uint8_t* __restrict__ s3m,
                                            const float* __restrict__ fw1T,
                                            const float* __restrict__ fb1,
                                            const float* __restrict__ fw2,
                                            const float* __restrict__ fb2,
                                            float* __restrict__ out) {
    __shared__ float red[3][64][65];
    int b = blockIdx.x;
    int w = threadIdx.x >> 6;                         // 0..3
    int lane = threadIdx.x & 63;
    float acc[8][8];                                  // [j][t]
    #pragma unroll
    for (int j = 0; j < 8; j++)
        #pragma unroll
        for (int t = 0; t < 8; t++) acc[j][t] = 0.f;

    int ibeg = w * 784;                               // 784 = 49*16
    for (int i0 = ibeg; i0 < ibeg + 784; i0 += 16) {
        int base = RFL(b * K + i0);
        const uint32_t* mp = (const uint32_t*)(s3m + base);
        #pragma unroll
        for (int d = 0; d < 4; d++) {
            uint32_t md = mp[d];
            if (md == 0) continue;
            #pragma unroll
            for (int q = 0; q < 4; q++) {
                uint32_t m = (md >> (q * 8)) & 0xffu;
                if (m == 0) continue;
                int i_our = i0 + d * 4 + q;           // = pix*64 + c
                int pix = i_our >> 6, c = i_our & 63;
                const float4* wp = (const float4*)(fw1T + (size_t)(c * 49 + pix) * O + lane * 8);
                float4 wa = wp[0], wb = wp[1];
                float wv[8] = {wa.x, wa.y, wa.z, wa.w, wb.x, wb.y, wb.z, wb.w};
                #pragma unroll
                for (int t = 0; t < 8; t++) {
                    if (m & (1u << t)) {
                        #pragma unroll
                        for (int j = 0; j < 8; j++) acc[j][t] += wv[j];
                    }
                }
            }
        }
    }

    if (w > 0) {
        #pragma unroll
        for (int j = 0; j < 8; j++)
            #pragma unroll
            for (int t = 0; t < 8; t++) red[w - 1][lane][j * 8 + t] = acc[j][t];
    }
    __syncthreads();
    if (w != 0) return;

    #pragma unroll
    for (int ww = 0; ww < 3; ww++)
        #pragma unroll
        for (int j = 0; j < 8; j++)
            #pragma unroll
            for (int t = 0; t < 8; t++) acc[j][t] += red[ww][lane][j * 8 + t];

    float msum[8];
    #pragma unroll
    for (int j = 0; j < 8; j++) {
        float yb = fb1[lane * 8 + j];
        float v = 0.f, cnt = 0.f;
        #pragma unroll
        for (int t = 0; t < 8; t++) {
            float y = acc[j][t] + yb;
            v = v + (y - v) * 0.5f;
            bool sp = (v >= 1.0f);
            cnt += sp ? 1.f : 0.f;
            v = sp ? 0.f : v;
        }
        msum[j] = cnt * 0.125f;                       // exact: count/8
    }
    #pragma unroll
    for (int k = 0; k < 6; k++) {
        const float* wr = fw2 + k * O + lane * 8;
        float pv = 0.f;
        #pragma unroll
        for (int j = 0; j < 8; j++) pv += msum[j] * wr[j];
        #pragma unroll
        for (int off = 32; off > 0; off >>= 1) pv += __shfl_down(pv, off, 64);
        if (lane == 0) out[b * 6 + k] = pv + fb2[k];
    }
}

// ---------------- launch ----------------
extern "C" void kernel_launch(void* const* d_in, const int* in_sizes, int n_in,
                              void* d_out, int out_size, void* d_ws, size_t ws_size,
                              hipStream_t stream) {
    const float* x   = (const float*)d_in[0];
    const float* w1  = (const float*)d_in[1];
    const float* b1  = (const float*)d_in[2];
    const float* w2  = (const float*)d_in[3];
    const float* b2  = (const float*)d_in[4];
    const float* w3  = (const float*)d_in[5];
    const float* b3  = (const float*)d_in[6];
    const float* fw1 = (const float*)d_in[7];
    const float* fb1 = (const float*)d_in[8];
    const float* fw2 = (const float*)d_in[9];
    const float* fb2 = (const float*)d_in[10];
    float* out = (float*)d_out;

    uint8_t* ws   = (uint8_t*)d_ws;
    uint8_t* s1c  = ws + OFF_S1;
    uint8_t* s2p  = ws + OFF_S2;
    uint8_t* s3m  = ws + OFF_S3;
    float*   w2T  = (float*)(ws + OFF_W2T);
    float*   w3T  = (float*)(ws + OFF_W3T);
    float*   fw1T = (float*)(ws + OFF_FW1T);
    float*   w1T  = (float*)(ws + OFF_W1T);

    hipLaunchKernelGGL(k_prep_w1,  dim3(32),    dim3(256), 0, stream, w1, w1T);
    hipLaunchKernelGGL(k_prep_w2,  dim3(128),   dim3(256), 0, stream, w2, w2T);
    hipLaunchKernelGGL(k_prep_w3,  dim3(144),   dim3(256), 0, stream, w3, w3T);
    hipLaunchKernelGGL(k_prep_fw1, dim3(392),   dim3(256), 0, stream, fw1, fw1T);
    hipLaunchKernelGGL(k_conv1,    dim3(1600),  dim3(256), 0, stream, x, w1T, b1, s1c);
    hipLaunchKernelGGL(k_conv2,    dim3(10368), dim3(256), 0, stream, s1c, w2T, b2, s2p);
    hipLaunchKernelGGL(k_conv3,    dim3(6272),  dim3(256), 0, stream, s2p, w3T, b3, s3m);
    hipLaunchKernelGGL(k_fc,       dim3(512),   dim3(256), 0, stream, s3m, fw1T, fb1, fw2, fb2, out);
}